// Round 1
// baseline (251.380 us; speedup 1.0000x reference)
//
#include <hip/hip_runtime.h>
#include <hip/hip_bf16.h>
#include <cstdint>
#include <cstddef>

#define B_SZ   2
#define T_CTX  2048
#define DIM_C  1024
#define NHEAD  16
#define HD     64
#define NBH    (B_SZ*NHEAD)

typedef __attribute__((ext_vector_type(8))) short short8;
typedef __attribute__((ext_vector_type(4))) float f32x4;

union BV8 { short8 s; __hip_bfloat16 h[8]; unsigned short u[8]; };

#define GLD16(gp, lp) \
  __builtin_amdgcn_global_load_lds((const __attribute__((address_space(1))) void*)(gp), \
                                   (__attribute__((address_space(3))) void*)(lp), 16, 0, 0)

// ---------------- fp32 -> bf16 convert ----------------
__global__ __launch_bounds__(256) void cvt_f32_bf16(const float* __restrict__ in,
                                                    __hip_bfloat16* __restrict__ out,
                                                    int n4) {
  int i = blockIdx.x * 256 + threadIdx.x;
  if (i >= n4) return;
  float4 v = reinterpret_cast<const float4*>(in)[i];
  BV8 o;
  o.h[0] = __float2bfloat16(v.x);
  o.h[1] = __float2bfloat16(v.y);
  o.h[2] = __float2bfloat16(v.z);
  o.h[3] = __float2bfloat16(v.w);
  ushort4 st = { o.u[0], o.u[1], o.u[2], o.u[3] };
  reinterpret_cast<ushort4*>(out)[i] = st;
}

// ---------------- bf16 GEMM, C = A[M,K] * Bt[N,K]^T ----------------
// 128x128 tile, BK=32, 4 waves (2x2), each wave 64x64 (4x4 of 16x16 frags)
template <typename OutT>
__global__ __launch_bounds__(256) void gemm_bt(const __hip_bfloat16* __restrict__ A,
                                               const __hip_bfloat16* __restrict__ Bt,
                                               OutT* __restrict__ C,
                                               int M, int N, int K) {
  __shared__ __align__(16) __hip_bfloat16 As[128 * 32];
  __shared__ __align__(16) __hip_bfloat16 Bs[128 * 32];
  const int tid = threadIdx.x;
  const int w = tid >> 6, l = tid & 63;
  const int l15 = l & 15, l4 = l >> 4;
  const int wr = w >> 1, wc = w & 1;
  const long bm = (long)blockIdx.y * 128;
  const long bn = (long)blockIdx.x * 128;

  f32x4 acc[4][4] = {};

  const int srow = tid >> 2;          // 0..63 (row within 64-row chunk)
  const int scol = (tid & 3) * 16;    // byte offset within 64B row
  char* AsB = (char*)As;
  char* BsB = (char*)Bs;
  const char* Ab  = (const char*)A;
  const char* Btb = (const char*)Bt;

  for (int kt = 0; kt < K; kt += 32) {
    __syncthreads();
#pragma unroll
    for (int it = 0; it < 2; ++it) {
      long arow = bm + it * 64 + srow;
      GLD16(Ab + (arow * K + kt) * 2 + scol, AsB + it * 4096 + w * 1024);
      long brow = bn + it * 64 + srow;
      GLD16(Btb + (brow * K + kt) * 2 + scol, BsB + it * 4096 + w * 1024);
    }
    __syncthreads();
    short8 aF[4], bF[4];
#pragma unroll
    for (int m = 0; m < 4; ++m)
      aF[m] = *(const short8*)(AsB + (wr * 64 + m * 16 + l15) * 64 + l4 * 16);
#pragma unroll
    for (int n = 0; n < 4; ++n)
      bF[n] = *(const short8*)(BsB + (wc * 64 + n * 16 + l15) * 64 + l4 * 16);
#pragma unroll
    for (int m = 0; m < 4; ++m)
#pragma unroll
      for (int n = 0; n < 4; ++n)
        acc[m][n] = __builtin_amdgcn_mfma_f32_16x16x32_bf16(aF[m], bF[n], acc[m][n], 0, 0, 0);
  }

#pragma unroll
  for (int m = 0; m < 4; ++m)
#pragma unroll
    for (int n = 0; n < 4; ++n)
#pragma unroll
      for (int r = 0; r < 4; ++r) {
        long row = bm + wr * 64 + m * 16 + l4 * 4 + r;
        long col = bn + wc * 64 + n * 16 + l15;
        float v = acc[m][n][r];
        if constexpr (sizeof(OutT) == 2) {
          C[row * N + col] = __float2bfloat16(v);
        } else {
          C[row * N + col] = v;
        }
      }
}

// ---------------- RoPE + repack: qkv[B*T][3072] -> Q,K [bh][t][64], VT [bh][d][t] ----------------
__global__ __launch_bounds__(256) void rope_pack(const __hip_bfloat16* __restrict__ qkv,
                                                 __hip_bfloat16* __restrict__ Qb,
                                                 __hip_bfloat16* __restrict__ Kb,
                                                 __hip_bfloat16* __restrict__ VTb) {
  __shared__ __hip_bfloat16 vt[64][72];  // padded to dodge bank conflicts
  const int bh = blockIdx.x;
  const int b = bh >> 4, h = bh & 15;
  const int t0 = blockIdx.y * 64;
  const int tid = threadIdx.x;

#pragma unroll
  for (int rep = 0; rep < 2; ++rep) {
    int idx = rep * 256 + tid;     // 0..511
    int tt = idx >> 3;             // 0..63
    int d0 = (idx & 7) * 8;        // 0,8,..,56
    int t = t0 + tt;
    size_t src = ((size_t)(b * T_CTX + t)) * 3072 + h * 64 + d0;
    BV8 qv, kv, vv, qo, ko;
    qv.s = *(const short8*)(qkv + src);
    kv.s = *(const short8*)(qkv + src + 1024);
    vv.s = *(const short8*)(qkv + src + 2048);
#pragma unroll
    for (int p = 0; p < 4; ++p) {
      int i = (d0 >> 1) + p;  // pair index 0..31
      // inv_freq = 10000^(-2i/64) = exp2(-log2(10000)*2i/64)
      float inv = exp2f(-13.287712379549449f * ((float)(2 * i) * (1.0f / 64.0f)));
      float ang = (float)t * inv;
      float sn, cn;
      sincosf(ang, &sn, &cn);
      float q1 = __bfloat162float(qv.h[2 * p]);
      float q2 = __bfloat162float(qv.h[2 * p + 1]);
      float k1 = __bfloat162float(kv.h[2 * p]);
      float k2 = __bfloat162float(kv.h[2 * p + 1]);
      // fold softmax scale 1/sqrt(64)=0.125 into Q
      qo.h[2 * p]     = __float2bfloat16((q1 * cn - q2 * sn) * 0.125f);
      qo.h[2 * p + 1] = __float2bfloat16((q1 * sn + q2 * cn) * 0.125f);
      ko.h[2 * p]     = __float2bfloat16(k1 * cn - k2 * sn);
      ko.h[2 * p + 1] = __float2bfloat16(k1 * sn + k2 * cn);
    }
    size_t dst = ((size_t)bh * T_CTX + t) * 64 + d0;
    *(short8*)(Qb + dst) = qo.s;
    *(short8*)(Kb + dst) = ko.s;
#pragma unroll
    for (int j = 0; j < 8; ++j) vt[d0 + j][tt] = vv.h[j];
  }
  __syncthreads();
#pragma unroll
  for (int rep = 0; rep < 2; ++rep) {
    int idx = rep * 256 + tid;
    int d = idx >> 3;
    int toff = (idx & 7) * 8;
    BV8 o;
#pragma unroll
    for (int j = 0; j < 8; ++j) o.h[j] = vt[d][toff + j];
    *(short8*)(VTb + ((size_t)bh * 64 + d) * T_CTX + t0 + toff) = o.s;
  }
}

// ---------------- flash attention (causal), 4 waves x 32 q-rows, KV tiles of 32 ----------------
__global__ __launch_bounds__(256) void flash_attn(const __hip_bfloat16* __restrict__ Qb,
                                                  const __hip_bfloat16* __restrict__ Kb,
                                                  const __hip_bfloat16* __restrict__ VTb,
                                                  __hip_bfloat16* __restrict__ Y) {
  __shared__ __align__(16) __hip_bfloat16 Ks[32 * 64];      // [k][d], XOR-swizzled rows (128B)
  __shared__ __align__(16) __hip_bfloat16 Vs[64 * 32];      // [d][k], XOR-swizzled rows (64B)
  __shared__ __align__(16) __hip_bfloat16 Ps[4][32 * 32];   // per-wave P staging, swizzled
  const int bh = blockIdx.y;
  const int b = bh >> 4, h = bh & 15;
  const int q0 = blockIdx.x * 128;
  const int tid = threadIdx.x;
  const int w = tid >> 6, l = tid & 63;
  const int l15 = l & 15, l4 = l >> 4;
  const int qw = q0 + w * 32;  // wave's q start

  // Q fragments in registers: [qtile][dslice]
  short8 qF[2][2];
#pragma unroll
  for (int qt = 0; qt < 2; ++qt)
#pragma unroll
    for (int ds = 0; ds < 2; ++ds)
      qF[qt][ds] = *(const short8*)(Qb + ((size_t)bh * T_CTX + qw + qt * 16 + l15) * 64 +
                                    ds * 32 + l4 * 8);

  f32x4 o[2][4] = {};
  float mrow[2][4], lrow[2][4];
#pragma unroll
  for (int qt = 0; qt < 2; ++qt)
#pragma unroll
    for (int r = 0; r < 4; ++r) { mrow[qt][r] = -1e30f; lrow[qt][r] = 0.0f; }

  char* KsB = (char*)Ks;
  char* VsB = (char*)Vs;
  char* PsB = (char*)(Ps[w]);

  const int srowK = tid >> 3, soffK = (tid & 7) * 16;  // K: 32 rows x 128B
  const int srowV = tid >> 2, soffV = (tid & 3) * 16;  // V: 64 rows x 64B

  const int ktiles = (q0 + 128) >> 5;
  for (int kt = 0; kt < ktiles; ++kt) {
    const int kv0 = kt << 5;
    __syncthreads();
    {
      short8 kstg = *(const short8*)((const char*)(Kb + ((size_t)bh * T_CTX + kv0 + srowK) * 64) + soffK);
      *(short8*)(KsB + srowK * 128 + (soffK ^ ((srowK & 7) << 4))) = kstg;
      short8 vstg = *(const short8*)((const char*)(VTb + ((size_t)bh * 64 + srowV) * T_CTX + kv0) + soffV);
      *(short8*)(VsB + srowV * 64 + (soffV ^ (((srowV >> 1) & 3) << 4))) = vstg;
    }
    __syncthreads();
    if (kv0 > qw + 31) continue;  // fully masked for this wave (wave-uniform)

    // QK^T -> s[qt][ntile(k)]
    short8 kF[2][2];
#pragma unroll
    for (int n = 0; n < 2; ++n) {
      int krow = n * 16 + l15;
#pragma unroll
      for (int ds = 0; ds < 2; ++ds)
        kF[n][ds] = *(const short8*)(KsB + krow * 128 + ((ds * 64 + l4 * 16) ^ ((krow & 7) << 4)));
    }
    f32x4 s[2][2] = {};
#pragma unroll
    for (int qt = 0; qt < 2; ++qt)
#pragma unroll
      for (int n = 0; n < 2; ++n)
#pragma unroll
        for (int ds = 0; ds < 2; ++ds)
          s[qt][n] = __builtin_amdgcn_mfma_f32_16x16x32_bf16(qF[qt][ds], kF[n][ds], s[qt][n], 0, 0, 0);

    if (kv0 + 31 > qw) {  // diagonal tile: causal mask
#pragma unroll
      for (int qt = 0; qt < 2; ++qt)
#pragma unroll
        for (int n = 0; n < 2; ++n)
#pragma unroll
          for (int r = 0; r < 4; ++r) {
            int qg = qw + qt * 16 + l4 * 4 + r;
            int kg = kv0 + n * 16 + l15;
            if (kg > qg) s[qt][n][r] = -1e30f;
          }
    }

    // online softmax (rows live across 16-lane groups)
#pragma unroll
    for (int qt = 0; qt < 2; ++qt) {
#pragma unroll
      for (int r = 0; r < 4; ++r) {
        float mx = fmaxf(s[qt][0][r], s[qt][1][r]);
        mx = fmaxf(mx, __shfl_xor(mx, 1));
        mx = fmaxf(mx, __shfl_xor(mx, 2));
        mx = fmaxf(mx, __shfl_xor(mx, 4));
        mx = fmaxf(mx, __shfl_xor(mx, 8));
        float mnew = fmaxf(mrow[qt][r], mx);
        float fac = __expf(mrow[qt][r] - mnew);
        mrow[qt][r] = mnew;
        float p0 = __expf(s[qt][0][r] - mnew);
        float p1 = __expf(s[qt][1][r] - mnew);
        s[qt][0][r] = p0;
        s[qt][1][r] = p1;
        float rs = p0 + p1;
        rs += __shfl_xor(rs, 1);
        rs += __shfl_xor(rs, 2);
        rs += __shfl_xor(rs, 4);
        rs += __shfl_xor(rs, 8);
        lrow[qt][r] = lrow[qt][r] * fac + rs;
#pragma unroll
        for (int nt = 0; nt < 4; ++nt) o[qt][nt][r] *= fac;
      }
    }

    // P (C-layout) -> LDS bf16 (swizzled) -> A-fragments
#pragma unroll
    for (int qt = 0; qt < 2; ++qt)
#pragma unroll
      for (int n = 0; n < 2; ++n)
#pragma unroll
        for (int r = 0; r < 4; ++r) {
          int prow = qt * 16 + l4 * 4 + r;
          int pcolb = (n * 16 + l15) * 2;
          *(__hip_bfloat16*)(PsB + prow * 64 + (pcolb ^ (((prow >> 1) & 3) << 4))) =
              __float2bfloat16(s[qt][n][r]);
        }
    short8 pF[2];
#pragma unroll
    for (int qt = 0; qt < 2; ++qt) {
      int prow = qt * 16 + l15;
      pF[qt] = *(const short8*)(PsB + prow * 64 + ((l4 * 16) ^ (((prow >> 1) & 3) << 4)));
    }
    short8 vF[4];
#pragma unroll
    for (int nt = 0; nt < 4; ++nt) {
      int d = nt * 16 + l15;
      vF[nt] = *(const short8*)(VsB + d * 64 + ((l4 * 16) ^ (((d >> 1) & 3) << 4)));
    }
#pragma unroll
    for (int qt = 0; qt < 2; ++qt)
#pragma unroll
      for (int nt = 0; nt < 4; ++nt)
        o[qt][nt] = __builtin_amdgcn_mfma_f32_16x16x32_bf16(pF[qt], vF[nt], o[qt][nt], 0, 0, 0);
  }

  // epilogue: Y[b][t][h*64+d] bf16
#pragma unroll
  for (int qt = 0; qt < 2; ++qt)
#pragma unroll
    for (int r = 0; r < 4; ++r) {
      float inv = 1.0f / lrow[qt][r];
      int qrow = qw + qt * 16 + l4 * 4 + r;
#pragma unroll
      for (int nt = 0; nt < 4; ++nt)
        Y[((size_t)(b * T_CTX + qrow)) * DIM_C + h * 64 + nt * 16 + l15] =
            __float2bfloat16(o[qt][nt][r] * inv);
    }
}

// ---------------- launcher ----------------
extern "C" void kernel_launch(void* const* d_in, const int* in_sizes, int n_in,
                              void* d_out, int out_size, void* d_ws, size_t ws_size,
                              hipStream_t stream) {
  const float* x     = (const float*)d_in[0];
  const float* qkv_w = (const float*)d_in[1];
  const float* out_w = (const float*)d_in[2];
  float* out = (float*)d_out;

  char* ws = (char*)d_ws;
  const size_t MB = 1024 * 1024;
  __hip_bfloat16* xb    = (__hip_bfloat16*)(ws + 0 * MB);   // 4M elems -> 8MB
  __hip_bfloat16* wqkvb = (__hip_bfloat16*)(ws + 8 * MB);   // 3M elems -> 6MB
  __hip_bfloat16* woutb = (__hip_bfloat16*)(ws + 14 * MB);  // 1M elems -> 2MB
  __hip_bfloat16* qkvb  = (__hip_bfloat16*)(ws + 16 * MB);  // 12M elems -> 24MB
  __hip_bfloat16* Qb    = (__hip_bfloat16*)(ws + 40 * MB);  // 4M elems -> 8MB
  __hip_bfloat16* Kb    = (__hip_bfloat16*)(ws + 48 * MB);  // 8MB
  __hip_bfloat16* VTb   = (__hip_bfloat16*)(ws + 56 * MB);  // 8MB
  __hip_bfloat16* yb    = (__hip_bfloat16*)(ws + 64 * MB);  // 8MB

  // convert inputs to bf16
  cvt_f32_bf16<<<4096, 256, 0, stream>>>(x, xb, 1048576);
  cvt_f32_bf16<<<3072, 256, 0, stream>>>(qkv_w, wqkvb, 786432);
  cvt_f32_bf16<<<1024, 256, 0, stream>>>(out_w, woutb, 262144);

  // qkv = x @ qkv_w^T : [4096,1024] x [3072,1024]^T -> [4096,3072] (bf16)
  gemm_bt<__hip_bfloat16><<<dim3(24, 32), 256, 0, stream>>>(xb, wqkvb, qkvb, 4096, 3072, 1024);

  // rope + repack into per-head layouts
  rope_pack<<<dim3(32, 32), 256, 0, stream>>>(qkvb, Qb, Kb, VTb);

  // causal flash attention -> y [B,T,C] bf16
  flash_attn<<<dim3(16, 32), 256, 0, stream>>>(Qb, Kb, VTb, yb);

  // out = y @ out_w^T : [4096,1024] x [1024,1024]^T -> [4096,1024] (fp32)
  gemm_bt<float><<<dim3(8, 32), 256, 0, stream>>>(yb, woutb, out, 4096, 1024, 1024);
}

// Round 2
// 150.669 us; speedup vs baseline: 1.6684x; 1.6684x over previous
//
#include <hip/hip_runtime.h>
#include <hip/hip_bf16.h>
#include <cstdint>
#include <cstddef>

#define B_SZ   2
#define T_CTX  2048
#define DIM_C  1024
#define NHEAD  16
#define HD     64
#define NBH    (B_SZ*NHEAD)

typedef __attribute__((ext_vector_type(8))) short short8;
typedef __attribute__((ext_vector_type(4))) float f32x4;

union BV8 { short8 s; __hip_bfloat16 h[8]; unsigned short u[8]; };
union U32x4 { uint32_t u[4]; short8 s8; };

#define GLD16(gp, lp) \
  __builtin_amdgcn_global_load_lds((const __attribute__((address_space(1))) void*)(gp), \
                                   (__attribute__((address_space(3))) void*)(lp), 16, 0, 0)

__device__ inline uint32_t pkbf(float a, float b) {
  union { __hip_bfloat16 h; unsigned short u; } ua, ub;
  ua.h = __float2bfloat16(a);
  ub.h = __float2bfloat16(b);
  return ((uint32_t)ub.u << 16) | (uint32_t)ua.u;
}

// ---------------- fp32 -> bf16 convert ----------------
__global__ __launch_bounds__(256) void cvt_f32_bf16(const float* __restrict__ in,
                                                    __hip_bfloat16* __restrict__ out,
                                                    int n4) {
  int i = blockIdx.x * 256 + threadIdx.x;
  if (i >= n4) return;
  float4 v = reinterpret_cast<const float4*>(in)[i];
  BV8 o;
  o.h[0] = __float2bfloat16(v.x);
  o.h[1] = __float2bfloat16(v.y);
  o.h[2] = __float2bfloat16(v.z);
  o.h[3] = __float2bfloat16(v.w);
  ushort4 st = { o.u[0], o.u[1], o.u[2], o.u[3] };
  reinterpret_cast<ushort4*>(out)[i] = st;
}

// ---------------- bf16 GEMM, C = A[M,K] * Bt[N,K]^T ----------------
template <typename OutT>
__global__ __launch_bounds__(256) void gemm_bt(const __hip_bfloat16* __restrict__ A,
                                               const __hip_bfloat16* __restrict__ Bt,
                                               OutT* __restrict__ C,
                                               int M, int N, int K) {
  __shared__ __align__(16) __hip_bfloat16 As[128 * 32];
  __shared__ __align__(16) __hip_bfloat16 Bs[128 * 32];
  const int tid = threadIdx.x;
  const int w = tid >> 6, l = tid & 63;
  const int l15 = l & 15, l4 = l >> 4;
  const int wr = w >> 1, wc = w & 1;
  const long bm = (long)blockIdx.y * 128;
  const long bn = (long)blockIdx.x * 128;

  f32x4 acc[4][4] = {};

  const int srow = tid >> 2;
  const int scol = (tid & 3) * 16;
  char* AsB = (char*)As;
  char* BsB = (char*)Bs;
  const char* Ab  = (const char*)A;
  const char* Btb = (const char*)Bt;

  for (int kt = 0; kt < K; kt += 32) {
    __syncthreads();
#pragma unroll
    for (int it = 0; it < 2; ++it) {
      long arow = bm + it * 64 + srow;
      GLD16(Ab + (arow * K + kt) * 2 + scol, AsB + it * 4096 + w * 1024);
      long brow = bn + it * 64 + srow;
      GLD16(Btb + (brow * K + kt) * 2 + scol, BsB + it * 4096 + w * 1024);
    }
    __syncthreads();
    short8 aF[4], bF[4];
#pragma unroll
    for (int m = 0; m < 4; ++m)
      aF[m] = *(const short8*)(AsB + (wr * 64 + m * 16 + l15) * 64 + l4 * 16);
#pragma unroll
    for (int n = 0; n < 4; ++n)
      bF[n] = *(const short8*)(BsB + (wc * 64 + n * 16 + l15) * 64 + l4 * 16);
#pragma unroll
    for (int m = 0; m < 4; ++m)
#pragma unroll
      for (int n = 0; n < 4; ++n)
        acc[m][n] = __builtin_amdgcn_mfma_f32_16x16x32_bf16(aF[m], bF[n], acc[m][n], 0, 0, 0);
  }

#pragma unroll
  for (int m = 0; m < 4; ++m)
#pragma unroll
    for (int n = 0; n < 4; ++n)
#pragma unroll
      for (int r = 0; r < 4; ++r) {
        long row = bm + wr * 64 + m * 16 + l4 * 4 + r;
        long col = bn + wc * 64 + n * 16 + l15;
        float v = acc[m][n][r];
        if constexpr (sizeof(OutT) == 2) {
          C[row * N + col] = __float2bfloat16(v);
        } else {
          C[row * N + col] = v;
        }
      }
}

// ---------------- RoPE + repack ----------------
__global__ __launch_bounds__(256) void rope_pack(const __hip_bfloat16* __restrict__ qkv,
                                                 __hip_bfloat16* __restrict__ Qb,
                                                 __hip_bfloat16* __restrict__ Kb,
                                                 __hip_bfloat16* __restrict__ VTb) {
  __shared__ __hip_bfloat16 vt[64][72];
  const int bh = blockIdx.x;
  const int b = bh >> 4, h = bh & 15;
  const int t0 = blockIdx.y * 64;
  const int tid = threadIdx.x;

#pragma unroll
  for (int rep = 0; rep < 2; ++rep) {
    int idx = rep * 256 + tid;
    int tt = idx >> 3;
    int d0 = (idx & 7) * 8;
    int t = t0 + tt;
    size_t src = ((size_t)(b * T_CTX + t)) * 3072 + h * 64 + d0;
    BV8 qv, kv, vv, qo, ko;
    qv.s = *(const short8*)(qkv + src);
    kv.s = *(const short8*)(qkv + src + 1024);
    vv.s = *(const short8*)(qkv + src + 2048);
#pragma unroll
    for (int p = 0; p < 4; ++p) {
      int i = (d0 >> 1) + p;
      float inv = exp2f(-13.287712379549449f * ((float)(2 * i) * (1.0f / 64.0f)));
      float ang = (float)t * inv;
      float sn, cn;
      sincosf(ang, &sn, &cn);
      float q1 = __bfloat162float(qv.h[2 * p]);
      float q2 = __bfloat162float(qv.h[2 * p + 1]);
      float k1 = __bfloat162float(kv.h[2 * p]);
      float k2 = __bfloat162float(kv.h[2 * p + 1]);
      qo.h[2 * p]     = __float2bfloat16((q1 * cn - q2 * sn) * 0.125f);
      qo.h[2 * p + 1] = __float2bfloat16((q1 * sn + q2 * cn) * 0.125f);
      ko.h[2 * p]     = __float2bfloat16(k1 * cn - k2 * sn);
      ko.h[2 * p + 1] = __float2bfloat16(k1 * sn + k2 * cn);
    }
    size_t dst = ((size_t)bh * T_CTX + t) * 64 + d0;
    *(short8*)(Qb + dst) = qo.s;
    *(short8*)(Kb + dst) = ko.s;
#pragma unroll
    for (int j = 0; j < 8; ++j) vt[d0 + j][tt] = vv.h[j];
  }
  __syncthreads();
#pragma unroll
  for (int rep = 0; rep < 2; ++rep) {
    int idx = rep * 256 + tid;
    int d = idx >> 3;
    int toff = (idx & 7) * 8;
    BV8 o;
#pragma unroll
    for (int j = 0; j < 8; ++j) o.h[j] = vt[d][toff + j];
    *(short8*)(VTb + ((size_t)bh * 64 + d) * T_CTX + t0 + toff) = o.s;
  }
}

// ---------------- flash attention (causal), swapped QK^T, KVBLK=64, dbuf ----------------
// 4 waves x 32 q-rows per block (q-range 128). S^T = mfma(K, Q^T): k lane-local.
__global__ __launch_bounds__(256) void flash_attn(const __hip_bfloat16* __restrict__ Qb,
                                                  const __hip_bfloat16* __restrict__ Kb,
                                                  const __hip_bfloat16* __restrict__ VTb,
                                                  __hip_bfloat16* __restrict__ Y) {
  // double buffer: buf b at b*16384: K [64][128B] then V [64][128B], linear LDS,
  // global source pre-swizzled with byte ^= ((row&7)<<4)
  __shared__ __align__(16) char smem[32768];
  const int bh = blockIdx.x;
  const int b = bh >> 4, h = bh & 15;
  const int q0 = ((int)gridDim.y - 1 - (int)blockIdx.y) * 128;  // longest blocks first
  const int tid = threadIdx.x;
  const int w = tid >> 6, l = tid & 63;
  const int l15 = l & 15, g = l >> 4;
  const int gh = g >> 1;
  const int srcA = l15 + ((g & 1) << 5);
  const int srcB = srcA + 16;
  const int qw = q0 + w * 32;

  // Q as B-operand fragments: B[d][q], q = l15, d = s*32 + g*8 + j
  short8 qB[2][2];
#pragma unroll
  for (int qt = 0; qt < 2; ++qt)
#pragma unroll
    for (int s = 0; s < 2; ++s)
      qB[qt][s] = *(const short8*)(Qb + ((size_t)bh * T_CTX + qw + qt * 16 + l15) * 64 +
                                   s * 32 + g * 8);

  f32x4 o[4][2] = {};  // O^T[dt][qt]: col=q=l15, row=d=g*4+r
  float mrow[2] = { -1e30f, -1e30f };
  float lrow[2] = { 0.0f, 0.0f };

  const int rowb = w * 8 + (l >> 3);
  const int colS = (l & 7) * 16;

  const int nt = (q0 + 128) >> 6;

  // prologue: stage tile 0 into buffer 0
#pragma unroll
  for (int rnd = 0; rnd < 2; ++rnd) {
    int row = rnd * 32 + rowb;
    int sw = colS ^ ((row & 7) << 4);
    GLD16((const char*)Kb + (((size_t)bh * T_CTX + row) << 7) + sw,
          smem + rnd * 4096 + w * 1024);
    GLD16((const char*)VTb + ((((size_t)bh * 64 + row) * T_CTX) << 1) + sw,
          smem + 8192 + rnd * 4096 + w * 1024);
  }

  int cur = 0;
  for (int t = 0; t < nt; ++t) {
    const int kv0 = t << 6;
    __syncthreads();  // buf[cur] ready (compiler drains vmcnt here)
    if (t + 1 < nt) {
      const int nkv0 = (t + 1) << 6;
#pragma unroll
      for (int rnd = 0; rnd < 2; ++rnd) {
        int row = rnd * 32 + rowb;
        int sw = colS ^ ((row & 7) << 4);
        GLD16((const char*)Kb + (((size_t)bh * T_CTX + nkv0 + row) << 7) + sw,
              smem + (cur ^ 1) * 16384 + rnd * 4096 + w * 1024);
        GLD16((const char*)VTb + ((((size_t)bh * 64 + row) * T_CTX + nkv0) << 1) + sw,
              smem + (cur ^ 1) * 16384 + 8192 + rnd * 4096 + w * 1024);
      }
    }
    if (kv0 <= qw + 31) {
      const char* KsB = smem + cur * 16384;
      const char* VsB = KsB + 8192;

      // QK^T (swapped): sT[kt][qt], k = kv0 + kt*16 + g*4 + r, q = qw + qt*16 + l15
      f32x4 sT[4][2] = {};
#pragma unroll
      for (int s = 0; s < 2; ++s) {
        short8 kA[4];
#pragma unroll
        for (int kt = 0; kt < 4; ++kt) {
          int R = kt * 16 + l15;
          kA[kt] = *(const short8*)(KsB + R * 128 + ((s * 64 + g * 16) ^ ((R & 7) << 4)));
        }
        __builtin_amdgcn_s_setprio(1);
#pragma unroll
        for (int kt = 0; kt < 4; ++kt)
#pragma unroll
          for (int qt = 0; qt < 2; ++qt)
            sT[kt][qt] = __builtin_amdgcn_mfma_f32_16x16x32_bf16(kA[kt], qB[qt][s], sT[kt][qt], 0, 0, 0);
        __builtin_amdgcn_s_setprio(0);
      }

      if (kv0 + 63 > qw) {  // diagonal region: causal mask
#pragma unroll
        for (int kt = 0; kt < 4; ++kt) {
          int kg = kv0 + kt * 16 + g * 4;
#pragma unroll
          for (int qt = 0; qt < 2; ++qt) {
            int qg = qw + qt * 16 + l15;
#pragma unroll
            for (int r = 0; r < 4; ++r)
              if (kg + r > qg) sT[kt][qt][r] = -1e30f;
          }
        }
      }

      // online softmax: k is lane-local (16 vals/lane/qt) + 2 shfl per reduce
      short8 pB[2][2];
#pragma unroll
      for (int qt = 0; qt < 2; ++qt) {
        float mx = sT[0][qt][0];
#pragma unroll
        for (int kt = 0; kt < 4; ++kt)
#pragma unroll
          for (int r = 0; r < 4; ++r) mx = fmaxf(mx, sT[kt][qt][r]);
        mx = fmaxf(mx, __shfl_xor(mx, 16));
        mx = fmaxf(mx, __shfl_xor(mx, 32));
        float mnew = fmaxf(mrow[qt], mx);
        float fac = __expf(mrow[qt] - mnew);
        mrow[qt] = mnew;
        float ps = 0.0f;
        uint32_t W[4][2];
#pragma unroll
        for (int kt = 0; kt < 4; ++kt) {
          float p0 = __expf(sT[kt][qt][0] - mnew);
          float p1 = __expf(sT[kt][qt][1] - mnew);
          float p2 = __expf(sT[kt][qt][2] - mnew);
          float p3 = __expf(sT[kt][qt][3] - mnew);
          ps += (p0 + p1) + (p2 + p3);
          W[kt][0] = pkbf(p0, p1);
          W[kt][1] = pkbf(p2, p3);
        }
        ps += __shfl_xor(ps, 16);
        ps += __shfl_xor(ps, 32);
        lrow[qt] = lrow[qt] * fac + ps;
#pragma unroll
        for (int dt = 0; dt < 4; ++dt)
#pragma unroll
          for (int r = 0; r < 4; ++r) o[dt][qt][r] *= fac;
        // repack P^T acc-layout -> B-frag (k = s*32 + g*8 + j) via lane gathers
#pragma unroll
        for (int s = 0; s < 2; ++s) {
          uint32_t a0 = (uint32_t)__shfl((int)W[2 * s][0], srcA);
          uint32_t a1 = (uint32_t)__shfl((int)W[2 * s][1], srcA);
          uint32_t b0 = (uint32_t)__shfl((int)W[2 * s + 1][0], srcA);
          uint32_t b1 = (uint32_t)__shfl((int)W[2 * s + 1][1], srcA);
          uint32_t c0 = (uint32_t)__shfl((int)W[2 * s][0], srcB);
          uint32_t c1 = (uint32_t)__shfl((int)W[2 * s][1], srcB);
          uint32_t d0 = (uint32_t)__shfl((int)W[2 * s + 1][0], srcB);
          uint32_t d1 = (uint32_t)__shfl((int)W[2 * s + 1][1], srcB);
          U32x4 u;
          u.u[0] = gh ? b0 : a0;
          u.u[1] = gh ? b1 : a1;
          u.u[2] = gh ? d0 : c0;
          u.u[3] = gh ? d1 : c1;
          pB[qt][s] = u.s8;
        }
      }

      // PV: O^T[dt][qt] += mfma(A=V^T, B=P^T)
#pragma unroll
      for (int s = 0; s < 2; ++s) {
        short8 vA[4];
#pragma unroll
        for (int dt = 0; dt < 4; ++dt) {
          int R = dt * 16 + l15;
          vA[dt] = *(const short8*)(VsB + R * 128 + ((s * 64 + g * 16) ^ ((R & 7) << 4)));
        }
        __builtin_amdgcn_s_setprio(1);
#pragma unroll
        for (int dt = 0; dt < 4; ++dt)
#pragma unroll
          for (int qt = 0; qt < 2; ++qt)
            o[dt][qt] = __builtin_amdgcn_mfma_f32_16x16x32_bf16(vA[dt], pB[qt][s], o[dt][qt], 0, 0, 0);
        __builtin_amdgcn_s_setprio(0);
      }
    }
    cur ^= 1;
  }

  // epilogue: O^T -> Y[b][q][h*64+d], d = dt*16 + g*4 + r (pack 4 -> 8B store)
#pragma unroll
  for (int qt = 0; qt < 2; ++qt) {
    float inv = 1.0f / lrow[qt];
    size_t rowoff = ((size_t)(b * T_CTX + qw + qt * 16 + l15)) * DIM_C + h * 64;
#pragma unroll
    for (int dt = 0; dt < 4; ++dt) {
      union { ushort4 v; unsigned short us[4]; } st;
#pragma unroll
      for (int r = 0; r < 4; ++r) {
        union { __hip_bfloat16 h; unsigned short u; } cv;
        cv.h = __float2bfloat16(o[dt][qt][r] * inv);
        st.us[r] = cv.u;
      }
      *(ushort4*)(Y + rowoff + dt * 16 + g * 4) = st.v;
    }
  }
}

// ---------------- launcher ----------------
extern "C" void kernel_launch(void* const* d_in, const int* in_sizes, int n_in,
                              void* d_out, int out_size, void* d_ws, size_t ws_size,
                              hipStream_t stream) {
  const float* x     = (const float*)d_in[0];
  const float* qkv_w = (const float*)d_in[1];
  const float* out_w = (const float*)d_in[2];
  float* out = (float*)d_out;

  char* ws = (char*)d_ws;
  const size_t MB = 1024 * 1024;
  __hip_bfloat16* xb    = (__hip_bfloat16*)(ws + 0 * MB);
  __hip_bfloat16* wqkvb = (__hip_bfloat16*)(ws + 8 * MB);
  __hip_bfloat16* woutb = (__hip_bfloat16*)(ws + 14 * MB);
  __hip_bfloat16* qkvb  = (__hip_bfloat16*)(ws + 16 * MB);
  __hip_bfloat16* Qb    = (__hip_bfloat16*)(ws + 40 * MB);
  __hip_bfloat16* Kb    = (__hip_bfloat16*)(ws + 48 * MB);
  __hip_bfloat16* VTb   = (__hip_bfloat16*)(ws + 56 * MB);
  __hip_bfloat16* yb    = (__hip_bfloat16*)(ws + 64 * MB);

  cvt_f32_bf16<<<4096, 256, 0, stream>>>(x, xb, 1048576);
  cvt_f32_bf16<<<3072, 256, 0, stream>>>(qkv_w, wqkvb, 786432);
  cvt_f32_bf16<<<1024, 256, 0, stream>>>(out_w, woutb, 262144);

  gemm_bt<__hip_bfloat16><<<dim3(24, 32), 256, 0, stream>>>(xb, wqkvb, qkvb, 4096, 3072, 1024);

  rope_pack<<<dim3(32, 32), 256, 0, stream>>>(qkvb, Qb, Kb, VTb);

  flash_attn<<<dim3(NBH, 16), 256, 0, stream>>>(Qb, Kb, VTb, yb);

  gemm_bt<float><<<dim3(8, 32), 256, 0, stream>>>(yb, woutb, out, 4096, 1024, 1024);
}